// Round 5
// baseline (102.184 us; speedup 1.0000x reference)
//
#include <hip/hip_runtime.h>
#include <stdint.h>

// Conv2d as implicit GEMM, bf16 MFMA, 256x256 tile, deep counted-vmcnt pipeline.
// x: [32,128,56,56] f32, w: [256,128,3,3] f32 -> out: [32,256,56,56] f32
// GEMM: M=100352, N=256, K=1152 (k=(kh*3+kw)*128+ci). 18 K-tiles of 64. Grid 392.

#define CIN   128
#define HW_   56
#define CO_   256
#define KSZ   1152
#define IMGHW 3136
#define HP    58
#define NT    18
#define BUFSZ 65536        // 4 planes x 16KB: A_kh0 A_kh1 B_kh0 B_kh1
#define XT_BYTES ((size_t)32 * HP * HP * CIN * 2)   // 27,557,888
#define WP_BYTES ((size_t)CO_ * KSZ * 2)            // 589,824
#define WS_NEED  (XT_BYTES + WP_BYTES)

typedef __attribute__((ext_vector_type(8))) __bf16 bf16x8;
typedef __attribute__((ext_vector_type(4))) float f32x4;
typedef __attribute__((ext_vector_type(8))) unsigned short ushort8;

__device__ __forceinline__ unsigned short f2bf(float f) {
    unsigned int u = __float_as_uint(f);
    u += 0x7fffu + ((u >> 16) & 1u);   // RNE
    return (unsigned short)(u >> 16);
}

__device__ __forceinline__ void gl2lds16(const void* g, void* l) {
    __builtin_amdgcn_global_load_lds(
        (const __attribute__((address_space(1))) void*)g,
        (__attribute__((address_space(3))) void*)l, 16, 0, 0);
}

// ---- weight pack: [co][ci][kh][kw] f32 -> [co][k] bf16, k=(kh*3+kw)*128+ci
__global__ void pack_weight(const float* __restrict__ w,
                            unsigned short* __restrict__ wp) {
    int idx = blockIdx.x * 256 + threadIdx.x;
    int co = idx / KSZ;
    int k  = idx - co * KSZ;
    int khkw = k >> 7;
    int ci = k & 127;
    wp[idx] = f2bf(w[(co * CIN + ci) * 9 + khkw]);
}

// ---- x transform: NCHW f32 -> padded NHWC bf16 [32][58][58][128]
__global__ __launch_bounds__(256)
void xform(const float* __restrict__ x, unsigned short* __restrict__ xt) {
    const int nb = blockIdx.x;
    const int n  = nb / HP;
    const int hp = nb - n * HP;
    unsigned short* orow = xt + ((size_t)n * HP + hp) * (HP * CIN);
    const int t = threadIdx.x;

    if (hp == 0 || hp == HP - 1) {
        for (int i = t; i < (HP * CIN) / 8; i += 256)
            ((ushort8*)orow)[i] = (ushort8){0, 0, 0, 0, 0, 0, 0, 0};
        return;
    }
    const int h = hp - 1;
    __shared__ unsigned short T[CIN][HP];
    const int wl = t & 63, cg = t >> 6;
    for (int c0 = 0; c0 < CIN; c0 += 4) {
        int ci = c0 + cg;
        if (wl < HW_)
            T[ci][wl] = f2bf(x[(((size_t)n * CIN + ci) * HW_ + h) * HW_ + wl]);
    }
    __syncthreads();
    const int ci = t & 127, wo = t >> 7;
    for (int wp_ = wo; wp_ < HP; wp_ += 2) {
        unsigned short v = 0;
        if (wp_ >= 1 && wp_ <= HW_) v = T[ci][wp_ - 1];
        orow[wp_ * CIN + ci] = v;
    }
}

// ---- main conv: 256x256 tile, BK=64, 8 waves (2m x 4n), wave 128x64
__global__ __launch_bounds__(512, 1)
void conv8(const unsigned short* __restrict__ xt,
           const unsigned short* __restrict__ wpk,
           float* __restrict__ out)
{
    // buf b at b*65536; planes: A_kh0 @0, A_kh1 @16K, B_kh0 @32K, B_kh1 @48K
    // plane layout: [256 rows][64 B], chunk c' = c ^ ((row>>1)&3)
    __shared__ __align__(16) char lds[2 * BUFSZ];   // 128 KiB

    const int tid  = threadIdx.x;
    const int lane = tid & 63;
    const int wid  = tid >> 6;

    int bid = blockIdx.x;
    bid = (bid & 7) * 49 + (bid >> 3);          // XCD swizzle, 392 = 8*49 bijective
    const int m0 = bid << 8;

    // ---- staging: thread writes row (tid>>2)+p*128, phys chunk tid&3 ----
    // source logical chunk = (tid&3) ^ ((row>>1)&3) = (tid&3) ^ ((tid>>3)&3)
    const uint32_t scb = (uint32_t)(((tid & 3) ^ ((tid >> 3) & 3)) << 4);
    uint32_t aoff[2], boff[2];
    #pragma unroll
    for (int p = 0; p < 2; ++p) {
        int r = p * 128 + (tid >> 2);
        int m = m0 + r;
        int n = m / IMGHW;
        int rem = m - n * IMGHW;
        int h = rem / HW_;
        int w = rem - h * HW_;
        aoff[p] = (uint32_t)(((n * HP + h) * HP + w) << 8) + scb;
        boff[p] = (uint32_t)(r * (KSZ * 2)) + scb;
    }

    // ---- fragment LDS offsets: row swizzle reduces to (fr>>1)&3 ----
    const int fr = lane & 15, fg = lane >> 4;
    const int fswz = ((fg ^ ((fr >> 1) & 3)) << 4);
    const int wm0 = (wid >> 2) << 7;            // 0 / 128
    const int wn0 = (wid & 3) << 6;             // 0..192
    const int aBase = (wm0 + fr) * 64 + fswz;           // + mf*1024 + kh*16384
    const int bBase = 32768 + (wn0 + fr) * 64 + fswz;   // + nf*1024 + kh*16384

    const char* xtc = (const char*)xt;
    const char* wpc = (const char*)wpk;

    f32x4 acc[8][4];
    #pragma unroll
    for (int i = 0; i < 8; ++i)
        #pragma unroll
        for (int j = 0; j < 4; ++j)
            acc[i][j] = (f32x4){0.f, 0.f, 0.f, 0.f};

    ushort8 areg[4], breg[4];

    // stage k-half kh of K-tile t into buf t&1: 4 loads/thread (wave-uniform)
    auto STAGE = [&](int t, int kh) {
        const int bufo = (t & 1) * BUFSZ;
        int tap = t >> 1;
        int khr = (tap * 11) >> 5;              // tap/3 for tap<9
        int kwr = tap - khr * 3;
        uint32_t asrc = (uint32_t)(((khr * HP + kwr) << 8) + ((t & 1) << 7) + (kh << 6));
        uint32_t bsrc = (uint32_t)((t << 7) + (kh << 6));
        #pragma unroll
        for (int p = 0; p < 2; ++p) {
            gl2lds16(xtc + aoff[p] + asrc,
                     &lds[bufo + kh * 16384 + p * 8192 + tid * 16]);
            gl2lds16(wpc + boff[p] + bsrc,
                     &lds[bufo + 32768 + kh * 16384 + p * 8192 + tid * 16]);
        }
    };

    #define LGKM0 do { asm volatile("s_waitcnt lgkmcnt(0)" ::: "memory"); \
                       __builtin_amdgcn_sched_barrier(0); } while (0)
    #define MM4(amf, r) do { \
        acc[amf][0] = __builtin_amdgcn_mfma_f32_16x16x32_bf16( \
            __builtin_bit_cast(bf16x8, breg[0]), __builtin_bit_cast(bf16x8, areg[r]), acc[amf][0], 0, 0, 0); \
        acc[amf][1] = __builtin_amdgcn_mfma_f32_16x16x32_bf16( \
            __builtin_bit_cast(bf16x8, breg[1]), __builtin_bit_cast(bf16x8, areg[r]), acc[amf][1], 0, 0, 0); \
        acc[amf][2] = __builtin_amdgcn_mfma_f32_16x16x32_bf16( \
            __builtin_bit_cast(bf16x8, breg[2]), __builtin_bit_cast(bf16x8, areg[r]), acc[amf][2], 0, 0, 0); \
        acc[amf][3] = __builtin_amdgcn_mfma_f32_16x16x32_bf16( \
            __builtin_bit_cast(bf16x8, breg[3]), __builtin_bit_cast(bf16x8, areg[r]), acc[amf][3], 0, 0, 0); \
    } while (0)

    // ---- prologue: (0,kh0),(0,kh1),(1,kh0); gate leaves (1,kh0) in flight ----
    STAGE(0, 0); STAGE(0, 1); STAGE(1, 0);
    asm volatile("s_waitcnt vmcnt(4)" ::: "memory");
    __builtin_amdgcn_s_barrier();

    for (int t = 0; t < NT; ++t) {
        const int bufo = (t & 1) * BUFSZ;
        const char* L = lds + bufo;

        // ===== P0: kh0, mf0-3 ; stage (t+1, kh1) =====
        breg[0] = *(const ushort8*)(L + bBase + 0 * 1024);
        breg[1] = *(const ushort8*)(L + bBase + 1 * 1024);
        breg[2] = *(const ushort8*)(L + bBase + 2 * 1024);
        breg[3] = *(const ushort8*)(L + bBase + 3 * 1024);
        areg[0] = *(const ushort8*)(L + aBase + 0 * 1024);
        areg[1] = *(const ushort8*)(L + aBase + 1 * 1024);
        areg[2] = *(const ushort8*)(L + aBase + 2 * 1024);
        areg[3] = *(const ushort8*)(L + aBase + 3 * 1024);
        if (t + 1 < NT) STAGE(t + 1, 1);        // buf[t+1] kh1: free since end P3(t-1)
        __builtin_amdgcn_s_barrier();
        LGKM0;
        __builtin_amdgcn_s_setprio(1);
        MM4(0, 0); MM4(1, 1); MM4(2, 2); MM4(3, 3);
        __builtin_amdgcn_s_setprio(0);
        __builtin_amdgcn_s_barrier();

        // ===== P1: kh0, mf4-7 =====
        areg[0] = *(const ushort8*)(L + aBase + 4 * 1024);
        areg[1] = *(const ushort8*)(L + aBase + 5 * 1024);
        areg[2] = *(const ushort8*)(L + aBase + 6 * 1024);
        areg[3] = *(const ushort8*)(L + aBase + 7 * 1024);
        __builtin_amdgcn_s_barrier();
        LGKM0;
        __builtin_amdgcn_s_setprio(1);
        MM4(4, 0); MM4(5, 1); MM4(6, 2); MM4(7, 3);
        __builtin_amdgcn_s_setprio(0);
        __builtin_amdgcn_s_barrier();

        // ===== P2: kh1, mf0-3 ; stage (t+2, kh0) =====
        breg[0] = *(const ushort8*)(L + bBase + 16384 + 0 * 1024);
        breg[1] = *(const ushort8*)(L + bBase + 16384 + 1 * 1024);
        breg[2] = *(const ushort8*)(L + bBase + 16384 + 2 * 1024);
        breg[3] = *(const ushort8*)(L + bBase + 16384 + 3 * 1024);
        areg[0] = *(const ushort8*)(L + aBase + 16384 + 0 * 1024);
        areg[1] = *(const ushort8*)(L + aBase + 16384 + 1 * 1024);
        areg[2] = *(const ushort8*)(L + aBase + 16384 + 2 * 1024);
        areg[3] = *(const ushort8*)(L + aBase + 16384 + 3 * 1024);
        if (t + 2 < NT) STAGE(t + 2, 0);        // buf[t] kh0: last read in P1
        __builtin_amdgcn_s_barrier();
        LGKM0;
        __builtin_amdgcn_s_setprio(1);
        MM4(0, 0); MM4(1, 1); MM4(2, 2); MM4(3, 3);
        __builtin_amdgcn_s_setprio(0);
        __builtin_amdgcn_s_barrier();

        // ===== P3: kh1, mf4-7 ; counted gate for tile t+1 =====
        areg[0] = *(const ushort8*)(L + aBase + 16384 + 4 * 1024);
        areg[1] = *(const ushort8*)(L + aBase + 16384 + 5 * 1024);
        areg[2] = *(const ushort8*)(L + aBase + 16384 + 6 * 1024);
        areg[3] = *(const ushort8*)(L + aBase + 16384 + 7 * 1024);
        __builtin_amdgcn_s_barrier();
        LGKM0;
        __builtin_amdgcn_s_setprio(1);
        MM4(4, 0); MM4(5, 1); MM4(6, 2); MM4(7, 3);
        __builtin_amdgcn_s_setprio(0);
        // (t+1) complete iff everything older than P2(t)'s 4 loads retired
        if (t + 2 < NT)      asm volatile("s_waitcnt vmcnt(4)" ::: "memory");
        else if (t + 1 < NT) asm volatile("s_waitcnt vmcnt(0)" ::: "memory");
        __builtin_amdgcn_s_barrier();
    }

    // ---- epilogue: direct stores; D row=co, col=m; lanes 0-15 contiguous in w
    const int mwave = m0 + wm0;
    const int co0 = wn0 + (fg << 2);
    #pragma unroll
    for (int mf = 0; mf < 8; ++mf) {
        int m = mwave + mf * 16 + fr;
        int n = m / IMGHW;
        int hwr = m - n * IMGHW;
        uint32_t basem = (uint32_t)(n * (CO_ * IMGHW) + hwr);
        #pragma unroll
        for (int nf = 0; nf < 4; ++nf)
            #pragma unroll
            for (int q = 0; q < 4; ++q)
                out[basem + (uint32_t)(co0 + nf * 16 + q) * IMGHW] = acc[mf][nf][q];
    }
    #undef LGKM0
    #undef MM4
}

// ================= fallback (round-1 kernel, used if ws too small) ==========
#define BM    64
#define BK    32
#define NSTEP 36
#define LDSP  40

template<bool PACKED>
__global__ __launch_bounds__(256, 2)
void conv_fb(const float* __restrict__ x,
             const float* __restrict__ wraw,
             const unsigned short* __restrict__ wp,
             float* __restrict__ out)
{
    __shared__ __align__(16) unsigned short Al[2][BM][LDSP];
    __shared__ __align__(16) unsigned short Bl[2][CO_][LDSP];

    const int tid  = threadIdx.x;
    const int lane = tid & 63;
    const int wid  = tid >> 6;

    const int mb    = blockIdx.x;
    const int n_img = mb / 49;
    const int hw0   = (mb - n_img * 49) * BM;

    const int mm = lane;
    const int hw = hw0 + mm;
    const int h  = hw / HW_;
    const int w_ = hw - h * HW_;

    const int bco  = tid >> 2;
    const int bkkg = tid & 3;

    float   aPF[8];
    ushort8 bPF[4];

    auto loadA = [&](int step) {
        int khkw = step >> 2;
        int kh = khkw / 3, kw = khkw - (khkw / 3) * 3;
        int ci0 = (step & 3) * BK + wid * 8;
        int ih = h + kh - 1, iw = w_ + kw - 1;
        bool valid = ((unsigned)ih < (unsigned)HW_) && ((unsigned)iw < (unsigned)HW_);
        const float* px = x + (((size_t)(n_img * CIN + ci0) * HW_ + ih) * HW_ + iw);
        #pragma unroll
        for (int e = 0; e < 8; ++e)
            aPF[e] = valid ? px[e * IMGHW] : 0.f;
    };
    auto writeA = [&](int buf) {
        ushort8 v;
        #pragma unroll
        for (int e = 0; e < 8; ++e) v[e] = f2bf(aPF[e]);
        *(ushort8*)&Al[buf][mm][wid * 8] = v;
    };
    auto loadB = [&](int step) {
        if (PACKED) {
            int k0 = step * BK;
            #pragma unroll
            for (int r = 0; r < 4; ++r)
                bPF[r] = *(const ushort8*)&wp[(r * 64 + bco) * KSZ + k0 + bkkg * 8];
        } else {
            int khkw = step >> 2;
            int ci0 = (step & 3) * BK + bkkg * 8;
            #pragma unroll
            for (int r = 0; r < 4; ++r) {
                int co = r * 64 + bco;
                ushort8 v;
                #pragma unroll
                for (int e = 0; e < 8; ++e)
                    v[e] = f2bf(wraw[(co * CIN + ci0 + e) * 9 + khkw]);
                bPF[r] = v;
            }
        }
    };
    auto writeB = [&](int buf) {
        #pragma unroll
        for (int r = 0; r < 4; ++r)
            *(ushort8*)&Bl[buf][r * 64 + bco][bkkg * 8] = bPF[r];
    };

    f32x4 acc[4][4];
    #pragma unroll
    for (int i = 0; i < 4; ++i)
        #pragma unroll
        for (int j = 0; j < 4; ++j)
            acc[i][j] = (f32x4){0.f, 0.f, 0.f, 0.f};

    const int frow = lane & 15;
    const int fk   = (lane >> 4) * 8;

    loadA(0); loadB(0);
    writeA(0); writeB(0);
    __syncthreads();

    for (int s = 0; s < NSTEP; ++s) {
        const int cur = s & 1;
        if (s + 1 < NSTEP) { loadA(s + 1); loadB(s + 1); }

        ushort8 aF[4], bF[4];
        #pragma unroll
        for (int i = 0; i < 4; ++i)
            aF[i] = *(const ushort8*)&Bl[cur][wid * 64 + i * 16 + frow][fk];
        #pragma unroll
        for (int j = 0; j < 4; ++j)
            bF[j] = *(const ushort8*)&Al[cur][j * 16 + frow][fk];

        #pragma unroll
        for (int i = 0; i < 4; ++i)
            #pragma unroll
            for (int j = 0; j < 4; ++j)
                acc[i][j] = __builtin_amdgcn_mfma_f32_16x16x32_bf16(
                    __builtin_bit_cast(bf16x8, aF[i]),
                    __builtin_bit_cast(bf16x8, bF[j]),
                    acc[i][j], 0, 0, 0);

        if (s + 1 < NSTEP) { writeA(cur ^ 1); writeB(cur ^ 1); }
        __syncthreads();
    }

    float* ob = out + (size_t)n_img * (CO_ * IMGHW) + hw0;
    #pragma unroll
    for (int i = 0; i < 4; ++i) {
        int co0 = wid * 64 + i * 16 + (lane >> 4) * 4;
        #pragma unroll
        for (int j = 0; j < 4; ++j) {
            int mcol = j * 16 + (lane & 15);
            #pragma unroll
            for (int q = 0; q < 4; ++q)
                ob[(size_t)(co0 + q) * IMGHW + mcol] = acc[i][j][q];
        }
    }
}

extern "C" void kernel_launch(void* const* d_in, const int* in_sizes, int n_in,
                              void* d_out, int out_size, void* d_ws, size_t ws_size,
                              hipStream_t stream) {
    (void)in_sizes; (void)n_in; (void)out_size;
    const float* x  = (const float*)d_in[0];
    const float* wt = (const float*)d_in[1];
    float* out = (float*)d_out;

    if (ws_size >= WS_NEED) {
        unsigned short* xt  = (unsigned short*)d_ws;
        unsigned short* wpk = (unsigned short*)((char*)d_ws + XT_BYTES);
        xform<<<32 * HP, 256, 0, stream>>>(x, xt);
        pack_weight<<<(CO_ * KSZ) / 256, 256, 0, stream>>>(wt, wpk);
        conv8<<<392, 512, 0, stream>>>(xt, wpk, out);
    } else if (ws_size >= WP_BYTES) {
        unsigned short* wpk = (unsigned short*)d_ws;
        pack_weight<<<(CO_ * KSZ) / 256, 256, 0, stream>>>(wt, wpk);
        conv_fb<true><<<100352 / BM, 256, 0, stream>>>(x, wt, wpk, out);
    } else {
        conv_fb<false><<<100352 / BM, 256, 0, stream>>>(x, wt, nullptr, out);
    }
}